// Round 13
// baseline (769.440 us; speedup 1.0000x reference)
//
#include <hip/hip_runtime.h>
#include <math.h>

typedef __attribute__((ext_vector_type(8))) short short8;
typedef __attribute__((ext_vector_type(4))) float f32x4;

#define B_ 16
#define T_ 256
#define I_ 64
#define H_ 128
#define K_ 64
#define U_ 256
#define KC 16
#define NTHR 256   /* 4 waves: halves per-CU LDS instruction load, keeps per-SIMD VALU same */

#define OUT_OFF_P (B_*T_*H_)              /* 524288 */
#define OUT_OFF_LW (OUT_OFF_P + B_*K_*H_) /* 655360 */

__device__ __forceinline__ unsigned short f2bf(float x) {
    unsigned int u = __float_as_uint(x);
    u += 0x7fffu + ((u >> 16) & 1u);   // RNE for finite inputs
    return (unsigned short)(u >> 16);
}
__device__ __forceinline__ float bf2f(unsigned short u) {
    return __uint_as_float(((unsigned int)u) << 16);
}
__device__ __forceinline__ float fast_tanh(float x) {
    float e = __expf(2.0f * x);
    return 1.0f - 2.0f * __builtin_amdgcn_rcpf(e + 1.0f);
}
__device__ __forceinline__ float fast_sigmoid(float x) {
    return __builtin_amdgcn_rcpf(1.0f + __expf(-x));
}
// XOR-swizzle (R3/R6-proven, bit4 only): breaks row-stride bank collisions on ds_read_b128
__device__ __forceinline__ unsigned int swzbyte_p(unsigned int row, unsigned int col) { // [16][128] bf16
    return (row * 256u + col * 2u) ^ ((row & 7u) << 4);
}
__device__ __forceinline__ unsigned int swzbyte_b(unsigned int row, unsigned int pos) { // [16][256] bf16, pos space
    return (row * 512u + pos * 2u) ^ ((row & 7u) << 4);
}

// raw barrier: LDS-visibility only; vmem (eps/xw prefetch, atomics) stays in flight.
#define BAR() do { asm volatile("s_waitcnt lgkmcnt(0)" ::: "memory"); \
                   __builtin_amdgcn_s_barrier(); \
                   asm volatile("" ::: "memory"); } while (0)

#define MFMA16(a, bfrag, c) __builtin_amdgcn_mfma_f32_16x16x32_bf16((a), (bfrag), (c), 0, 0, 0)

// ---------------- kernel 1: xw[b,t,u] = x[b,t,:] @ Wb[0:64,:] + bb  (bf16) ----------------
__global__ __launch_bounds__(256) void xw_kernel(
    const float* __restrict__ x, const float* __restrict__ Wb,
    const float* __restrict__ bb, unsigned short* __restrict__ xw)
{
    const int tid  = threadIdx.x;
    const int lane = tid & 63;
    const int wv   = tid >> 6;       // 0..3, owns cols [wv*64, +64)
    const int ln15 = lane & 15;
    const int l4   = lane >> 4;
    const int bid  = blockIdx.x;     // 256 blocks = b(16) x ttile(16)
    const int b    = bid >> 4;
    const int t0   = (bid & 15) * 16;

    short8 Bx[2][4];
    float bbc[4];
    #pragma unroll
    for (int kt = 0; kt < 2; ++kt) {
        #pragma unroll
        for (int ct = 0; ct < 4; ++ct) {
            short8 f;
            const int col = wv * 64 + ct * 16 + ln15;
            #pragma unroll
            for (int j = 0; j < 8; ++j)
                f[j] = (short)f2bf(Wb[(kt * 32 + l4 * 8 + j) * U_ + col]);
            Bx[kt][ct] = f;
        }
    }
    #pragma unroll
    for (int ct = 0; ct < 4; ++ct) bbc[ct] = bb[wv * 64 + ct * 16 + ln15];

    short8 ax[2];
    #pragma unroll
    for (int kt = 0; kt < 2; ++kt) {
        const float* xp = &x[(size_t)(b * T_ + t0 + ln15) * I_ + kt * 32 + l4 * 8];
        short8 f;
        #pragma unroll
        for (int j = 0; j < 8; ++j) f[j] = (short)f2bf(xp[j]);
        ax[kt] = f;
    }
    const f32x4 z4 = {0.f, 0.f, 0.f, 0.f};
    f32x4 acc[4] = {z4, z4, z4, z4};
    #pragma unroll
    for (int kt = 0; kt < 2; ++kt) {
        #pragma unroll
        for (int ct = 0; ct < 4; ++ct) acc[ct] = MFMA16(ax[kt], Bx[kt][ct], acc[ct]);
    }
    #pragma unroll
    for (int ct = 0; ct < 4; ++ct) {
        #pragma unroll
        for (int r = 0; r < 4; ++r) {
            const int trow = t0 + l4 * 4 + r;
            xw[(size_t)(b * T_ + trow) * U_ + wv * 64 + ct * 16 + ln15] = f2bf(acc[ct][r] + bbc[ct]);
        }
    }
}

// ---------------- kernel 2: the recurrence (4 waves, 2-barrier) ----------------
__global__ __launch_bounds__(NTHR, 1) void pf_kernel(
    const unsigned short* __restrict__ xw, const float* __restrict__ tspan,
    const float* __restrict__ eps, const float* __restrict__ Wb,
    const float* __restrict__ Wf1, const float* __restrict__ bf1,
    const float* __restrict__ Wf2, const float* __restrict__ bf2,
    const float* __restrict__ Wta, const float* __restrict__ bta,
    const float* __restrict__ Wtb, const float* __restrict__ btb,
    const float* __restrict__ nscale, float* __restrict__ out)
{
    const int tid  = threadIdx.x;
    const int lane = tid & 63;
    const int wv   = tid >> 6;        // wave 0..3
    const int ln15 = lane & 15;
    const int l4   = lane >> 4;
    const int bid  = blockIdx.x;      // 0..63
    const int b    = bid >> 2;
    const int k0   = (bid & 3) * KC;

    __shared__ unsigned short p_bf[KC * H_];     // particles bf16, swizzled (4KB)
    __shared__ unsigned short bbk_bf[KC * U_];   // backbone acts bf16, swizzled + col-pair-permuted (8KB)
    __shared__ float ts_lds[T_];                 // (1KB)

    for (int i = tid; i < KC * H_; i += NTHR) p_bf[i] = 0;
    for (int i = tid; i < T_; i += NTHR) ts_lds[i] = tspan[b * T_ + i];

    // ---- GEMM1 particle-part weights (Wb rows 64..191), wave owns bbk cols [wv*64,+64) ----
    short8 B1p[4][4];
    #pragma unroll
    for (int kt = 0; kt < 4; ++kt) {
        #pragma unroll
        for (int ct = 0; ct < 4; ++ct) {
            short8 f;
            const int col = wv * 64 + ct * 16 + ln15;
            #pragma unroll
            for (int j = 0; j < 8; ++j)
                f[j] = (short)f2bf(Wb[(I_ + kt * 32 + l4 * 8 + j) * U_ + col]);
            B1p[kt][ct] = f;
        }
    }
    // ---- GEMM2 weights: wave owns h cols [wv*32,+32) for ALL 4 heads ----
    // bbk LDS is column-PERMUTED within each 32-block: col c -> pos 2*(c&15)+((c>>4)&1),
    // so B-fragment element j (pos = l4*8+j) maps to k = kt*32 + (pos>>1) + ((pos&1)<<4). (R4/R6-verified)
    const float* Whp[4] = {Wf1, Wf2, Wta, Wtb};
    short8 B2[4][8][2];
    #pragma unroll
    for (int hd = 0; hd < 4; ++hd) {
        #pragma unroll
        for (int kt = 0; kt < 8; ++kt) {
            #pragma unroll
            for (int c2 = 0; c2 < 2; ++c2) {
                short8 f;
                const int hc2 = wv * 32 + c2 * 16 + ln15;
                #pragma unroll
                for (int j = 0; j < 8; ++j) {
                    const int pos = l4 * 8 + j;
                    const int kg  = kt * 32 + (pos >> 1) + ((pos & 1) << 4);
                    f[j] = (short)f2bf(Whp[hd][kg * H_ + hc2]);
                }
                B2[hd][kt][c2] = f;
            }
        }
    }
    float bf1c[2], bf2c[2], btac[2], btbc[2], nscc[2];
    #pragma unroll
    for (int c2 = 0; c2 < 2; ++c2) {
        const int hc2 = wv * 32 + c2 * 16 + ln15;
        bf1c[c2] = bf1[hc2]; bf2c[c2] = bf2[hc2];
        btac[c2] = bta[hc2]; btbc[c2] = btb[hc2];
        nscc[c2] = nscale[hc2];
    }

    if ((bid & 3) == 0 && tid < K_)
        out[OUT_OFF_LW + b * K_ + tid] = -4.1588830833596715f; // -log(64)

    __syncthreads();   // full drain once after prologue

    // per-step scalar operands, prefetched one step ahead into registers
    const float* ep0 = eps + ((size_t)(b * K_ + k0 + l4 * 4)) * H_ + wv * 32 + ln15; // + t*B*K*H, +16 for c2=1
    const unsigned short* xwp = xw + (size_t)b * T_ * U_ + wv * 64 + ln15;           // + t*U, +ct*16
    float ecur[2][4];
    #pragma unroll
    for (int c2 = 0; c2 < 2; ++c2)
        #pragma unroll
        for (int r = 0; r < 4; ++r) ecur[c2][r] = ep0[c2 * 16 + r * H_];
    float xwc[4];
    #pragma unroll
    for (int ct = 0; ct < 4; ++ct) xwc[ct] = bf2f(xwp[ct * 16]);
    float tscur = ts_lds[0];

    const f32x4 zero4 = {0.f, 0.f, 0.f, 0.f};

    for (int t = 0; t < T_; ++t) {
        // ---- prefetch step t+1 inputs (in flight across BARs; consumed next iter) ----
        const int tn = (t + 1 < T_) ? t + 1 : t;
        const float* epn = ep0 + (size_t)tn * (B_ * K_ * H_);
        float enext[2][4];
        #pragma unroll
        for (int c2 = 0; c2 < 2; ++c2)
            #pragma unroll
            for (int r = 0; r < 4; ++r) enext[c2][r] = epn[c2 * 16 + r * H_];
        float xwn[4];
        #pragma unroll
        for (int ct = 0; ct < 4; ++ct) xwn[ct] = bf2f(xwp[tn * U_ + ct * 16]);
        const float tsn = ts_lds[tn];

        // ---- ph1: GEMM1 particle part, 4 col-tiles; acc init = xw (precomputed x-part+bias) ----
        f32x4 acc[4];
        #pragma unroll
        for (int ct = 0; ct < 4; ++ct) { f32x4 v = {xwc[ct], xwc[ct], xwc[ct], xwc[ct]}; acc[ct] = v; }
        #pragma unroll
        for (int kt = 0; kt < 4; ++kt) {
            const short8 ap = *(const short8*)((const char*)p_bf + swzbyte_p(ln15, kt * 32 + l4 * 8));
            #pragma unroll
            for (int ct = 0; ct < 4; ++ct) acc[ct] = MFMA16(ap, B1p[kt][ct], acc[ct]);
        }
        #pragma unroll
        for (int r = 0; r < 4; ++r) {                 // C: row=(l>>4)*4+r, col=l&15
            const int row = l4 * 4 + r;
            const unsigned int q0 = f2bf(1.7159f * fast_tanh(0.666f * acc[0][r]));
            const unsigned int q1 = f2bf(1.7159f * fast_tanh(0.666f * acc[1][r]));
            const unsigned int q2 = f2bf(1.7159f * fast_tanh(0.666f * acc[2][r]));
            const unsigned int q3 = f2bf(1.7159f * fast_tanh(0.666f * acc[3][r]));
            // packed b32 writes: 32-block 2wv holds cols (wv*64+ln15, +16) -> pos wv*64+2*ln15(+1);
            //                    32-block 2wv+1 holds cols (+32, +48)     -> pos wv*64+32+2*ln15(+1)
            *(unsigned int*)((char*)bbk_bf + swzbyte_b(row, wv * 64 + 2 * ln15))      = q0 | (q1 << 16);
            *(unsigned int*)((char*)bbk_bf + swzbyte_b(row, wv * 64 + 32 + 2 * ln15)) = q2 | (q3 << 16);
        }
        BAR();   // bbk visible

        // ---- ph2: GEMM2 (4 heads x 2 col-tiles) + in-register combine ----
        f32x4 af1[2] = {zero4, zero4}, af2[2] = {zero4, zero4};
        f32x4 ata[2] = {zero4, zero4}, atb[2] = {zero4, zero4};
        #pragma unroll
        for (int kt = 0; kt < 8; ++kt) {
            const short8 a = *(const short8*)((const char*)bbk_bf + swzbyte_b(ln15, kt * 32 + l4 * 8));
            #pragma unroll
            for (int c2 = 0; c2 < 2; ++c2) {
                af1[c2] = MFMA16(a, B2[0][kt][c2], af1[c2]);
                af2[c2] = MFMA16(a, B2[1][kt][c2], af2[c2]);
                ata[c2] = MFMA16(a, B2[2][kt][c2], ata[c2]);
                atb[c2] = MFMA16(a, B2[3][kt][c2], atb[c2]);
            }
        }
        const float sq = sqrtf(tscur);
        float ps[2] = {0.f, 0.f};
        const bool last = (t == T_ - 1);
        #pragma unroll
        for (int c2 = 0; c2 < 2; ++c2) {
            const int hc2 = wv * 32 + c2 * 16 + ln15;
            #pragma unroll
            for (int r = 0; r < 4; ++r) {
                const int row = l4 * 4 + r;
                const float f1v = fast_tanh(af1[c2][r] + bf1c[c2]);
                const float f2v = fast_tanh(af2[c2][r] + bf2c[c2]);
                const float tiv = fast_sigmoid((ata[c2][r] + btac[c2]) * tscur + (atb[c2][r] + btbc[c2]));
                const float np  = f1v + tiv * (f2v - f1v) + nscc[c2] * sq * ecur[c2][r];
                *(unsigned short*)((char*)p_bf + swzbyte_p(row, hc2)) = f2bf(np);
                ps[c2] += np;
                if (last)
                    out[OUT_OFF_P + (size_t)(b * K_ + k0 + row) * H_ + hc2] = np;
            }
        }
        // block partial mean (16 rows): sum over l4 groups, 2 atomics per 16 lanes
        #pragma unroll
        for (int c2 = 0; c2 < 2; ++c2) {
            float p2 = ps[c2];
            p2 += __shfl_xor(p2, 16);
            p2 += __shfl_xor(p2, 32);
            if (lane < 16)
                atomicAdd(&out[(size_t)(b * T_ + t) * H_ + wv * 32 + c2 * 16 + lane], p2 * (1.0f / 64.0f));
        }

        #pragma unroll
        for (int c2 = 0; c2 < 2; ++c2)
            #pragma unroll
            for (int r = 0; r < 4; ++r) ecur[c2][r] = enext[c2][r];
        #pragma unroll
        for (int ct = 0; ct < 4; ++ct) xwc[ct] = xwn[ct];
        tscur = tsn;
        BAR();   // p writes visible for next step's ph1
    }
}

extern "C" void kernel_launch(void* const* d_in, const int* in_sizes, int n_in,
                              void* d_out, int out_size, void* d_ws, size_t ws_size,
                              hipStream_t stream) {
    const float* x    = (const float*)d_in[0];
    const float* tsp  = (const float*)d_in[1];
    const float* eps  = (const float*)d_in[2];
    const float* Wb   = (const float*)d_in[3];
    const float* bb   = (const float*)d_in[4];
    const float* Wf1  = (const float*)d_in[5];
    const float* bf1  = (const float*)d_in[6];
    const float* Wf2  = (const float*)d_in[7];
    const float* bf2  = (const float*)d_in[8];
    const float* Wta  = (const float*)d_in[9];
    const float* bta  = (const float*)d_in[10];
    const float* Wtb  = (const float*)d_in[11];
    const float* btb  = (const float*)d_in[12];
    const float* nsc  = (const float*)d_in[13];
    float* out = (float*)d_out;
    unsigned short* xw = (unsigned short*)d_ws;   // B*T*U bf16 = 2MB scratch

    // outputs region is accumulated with atomics -> zero every launch
    (void)hipMemsetAsync(d_out, 0, (size_t)OUT_OFF_P * sizeof(float), stream);
    xw_kernel<<<dim3(256), dim3(256), 0, stream>>>(x, Wb, bb, xw);
    pf_kernel<<<dim3(64), dim3(NTHR), 0, stream>>>(
        xw, tsp, eps, Wb, Wf1, bf1, Wf2, bf2, Wta, bta, Wtb, btb, nsc, out);
}

// Round 15
// 552.491 us; speedup vs baseline: 1.3927x; 1.3927x over previous
//
#include <hip/hip_runtime.h>
#include <math.h>

typedef __attribute__((ext_vector_type(8))) short short8;
typedef __attribute__((ext_vector_type(4))) float f32x4;

#define B_ 16
#define T_ 256
#define I_ 64
#define H_ 128
#define K_ 64
#define U_ 256
#define KC 16
#define NTHR 512

#define OUT_OFF_P (B_*T_*H_)              /* 524288 */
#define OUT_OFF_LW (OUT_OFF_P + B_*K_*H_) /* 655360 */

__device__ __forceinline__ unsigned short f2bf(float x) {
    unsigned int u = __float_as_uint(x);
    u += 0x7fffu + ((u >> 16) & 1u);   // RNE for finite inputs
    return (unsigned short)(u >> 16);
}
__device__ __forceinline__ float bf2f(unsigned short u) {
    return __uint_as_float(((unsigned int)u) << 16);
}
__device__ __forceinline__ float fast_tanh(float x) {
    float e = __expf(2.0f * x);
    return 1.0f - 2.0f * __builtin_amdgcn_rcpf(e + 1.0f);
}
__device__ __forceinline__ float fast_sigmoid(float x) {
    return __builtin_amdgcn_rcpf(1.0f + __expf(-x));
}
// XOR-swizzle (R3/R6-proven, bit4 only): breaks row-stride bank collisions on ds_read_b128
__device__ __forceinline__ unsigned int swzbyte_p(unsigned int row, unsigned int col) { // [16][128] bf16
    return (row * 256u + col * 2u) ^ ((row & 7u) << 4);
}
__device__ __forceinline__ unsigned int swzbyte_b(unsigned int row, unsigned int pos) { // [16][256] bf16, pos space
    return (row * 512u + pos * 2u) ^ ((row & 7u) << 4);
}

// raw barrier: LDS-visibility only; vmem (eps/xw prefetch, atomics) stays in flight.
#define BAR() do { asm volatile("s_waitcnt lgkmcnt(0)" ::: "memory"); \
                   __builtin_amdgcn_s_barrier(); \
                   asm volatile("" ::: "memory"); } while (0)

#define MFMA16(a, bfrag, c) __builtin_amdgcn_mfma_f32_16x16x32_bf16((a), (bfrag), (c), 0, 0, 0)

// ---------------- kernel 1: xw[b,t,u] = x[b,t,:] @ Wb[0:64,:] + bb  (bf16) ----------------
__global__ __launch_bounds__(256) void xw_kernel(
    const float* __restrict__ x, const float* __restrict__ Wb,
    const float* __restrict__ bb, unsigned short* __restrict__ xw)
{
    const int tid  = threadIdx.x;
    const int lane = tid & 63;
    const int wv   = tid >> 6;       // 0..3, owns cols [wv*64, +64)
    const int ln15 = lane & 15;
    const int l4   = lane >> 4;
    const int bid  = blockIdx.x;     // 256 blocks = b(16) x ttile(16)
    const int b    = bid >> 4;
    const int t0   = (bid & 15) * 16;

    short8 Bx[2][4];
    float bbc[4];
    #pragma unroll
    for (int kt = 0; kt < 2; ++kt) {
        #pragma unroll
        for (int ct = 0; ct < 4; ++ct) {
            short8 f;
            const int col = wv * 64 + ct * 16 + ln15;
            #pragma unroll
            for (int j = 0; j < 8; ++j)
                f[j] = (short)f2bf(Wb[(kt * 32 + l4 * 8 + j) * U_ + col]);
            Bx[kt][ct] = f;
        }
    }
    #pragma unroll
    for (int ct = 0; ct < 4; ++ct) bbc[ct] = bb[wv * 64 + ct * 16 + ln15];

    short8 ax[2];
    #pragma unroll
    for (int kt = 0; kt < 2; ++kt) {
        const float* xp = &x[(size_t)(b * T_ + t0 + ln15) * I_ + kt * 32 + l4 * 8];
        short8 f;
        #pragma unroll
        for (int j = 0; j < 8; ++j) f[j] = (short)f2bf(xp[j]);
        ax[kt] = f;
    }
    const f32x4 z4 = {0.f, 0.f, 0.f, 0.f};
    f32x4 acc[4] = {z4, z4, z4, z4};
    #pragma unroll
    for (int kt = 0; kt < 2; ++kt) {
        #pragma unroll
        for (int ct = 0; ct < 4; ++ct) acc[ct] = MFMA16(ax[kt], Bx[kt][ct], acc[ct]);
    }
    #pragma unroll
    for (int ct = 0; ct < 4; ++ct) {
        #pragma unroll
        for (int r = 0; r < 4; ++r) {
            const int trow = t0 + l4 * 4 + r;
            xw[(size_t)(b * T_ + trow) * U_ + wv * 64 + ct * 16 + ln15] = f2bf(acc[ct][r] + bbc[ct]);
        }
    }
}

// ---------------- kernel 2: the recurrence (R6 base + deferred reduce + packed bbk write) ----------------
__global__ __launch_bounds__(NTHR, 2) void pf_kernel(
    const unsigned short* __restrict__ xw, const float* __restrict__ tspan,
    const float* __restrict__ eps, const float* __restrict__ Wb,
    const float* __restrict__ Wf1, const float* __restrict__ bf1,
    const float* __restrict__ Wf2, const float* __restrict__ bf2,
    const float* __restrict__ Wta, const float* __restrict__ bta,
    const float* __restrict__ Wtb, const float* __restrict__ btb,
    const float* __restrict__ nscale, float* __restrict__ out)
{
    const int tid  = threadIdx.x;
    const int lane = tid & 63;
    const int wv   = tid >> 6;        // wave 0..7
    const int ln15 = lane & 15;
    const int l4   = lane >> 4;
    const int bid  = blockIdx.x;      // 0..63
    const int b    = bid >> 2;
    const int k0   = (bid & 3) * KC;

    __shared__ unsigned short p_bf[KC * H_];     // particles bf16, swizzled (4KB)
    __shared__ unsigned short bbk_bf[KC * U_];   // backbone acts bf16, swizzled + col-pair-permuted (8KB)
    __shared__ float ts_lds[T_];                 // (1KB)

    for (int i = tid; i < KC * H_; i += NTHR) p_bf[i] = 0;
    for (int i = tid; i < T_; i += NTHR) ts_lds[i] = tspan[b * T_ + i];

    // ---- GEMM1 particle-part weights (Wb rows 64..191), wave owns bbk cols [wv*32,+32) ----
    short8 B1p[4][2];
    #pragma unroll
    for (int kt = 0; kt < 4; ++kt) {
        #pragma unroll
        for (int ct = 0; ct < 2; ++ct) {
            short8 f;
            const int col = wv * 32 + ct * 16 + ln15;
            #pragma unroll
            for (int j = 0; j < 8; ++j)
                f[j] = (short)f2bf(Wb[(I_ + kt * 32 + l4 * 8 + j) * U_ + col]);
            B1p[kt][ct] = f;
        }
    }
    // ---- GEMM2 weights: wave owns h cols [wv*16,+16) for ALL 4 heads ----
    // bbk LDS is column-PERMUTED within each 32-block: col c -> pos 2*(c&15)+(c>>4),
    // so B-fragment element j (pos = l4*8+j) maps to k = kt*32 + (pos>>1) + ((pos&1)<<4).
    // (mapping correctness-verified in R4/R9 runs: absmax unchanged)
    const float* Whp[4] = {Wf1, Wf2, Wta, Wtb};
    const int hc = wv * 16 + ln15;
    short8 B2[4][8];
    #pragma unroll
    for (int hd = 0; hd < 4; ++hd) {
        #pragma unroll
        for (int kt = 0; kt < 8; ++kt) {
            short8 f;
            #pragma unroll
            for (int j = 0; j < 8; ++j) {
                const int pos = l4 * 8 + j;
                const int kg  = kt * 32 + (pos >> 1) + ((pos & 1) << 4);
                f[j] = (short)f2bf(Whp[hd][kg * H_ + hc]);
            }
            B2[hd][kt] = f;
        }
    }
    const float bf1c = bf1[hc], bf2c = bf2[hc];
    const float btac = bta[hc], btbc = btb[hc];
    const float nscc = nscale[hc];

    if ((bid & 3) == 0 && tid < K_)
        out[OUT_OFF_LW + b * K_ + tid] = -4.1588830833596715f; // -log(64)

    __syncthreads();   // full drain once after prologue

    // per-step scalar operands, prefetched one step ahead into registers
    const float* ep0 = eps + ((size_t)(b * K_ + k0 + l4 * 4)) * H_ + hc;        // + t*B*K*H
    const unsigned short* xwp = xw + (size_t)b * T_ * U_ + wv * 32 + ln15;      // + t*U  (+16 for ct=1)
    float ecur[4];
    #pragma unroll
    for (int r = 0; r < 4; ++r) ecur[r] = ep0[r * H_];
    float xw0c = bf2f(xwp[0]), xw1c = bf2f(xwp[16]);
    float tscur = ts_lds[0];

    const f32x4 zero4 = {0.f, 0.f, 0.f, 0.f};
    float psum_d = 0.f;   // deferred block-mean contribution (reduced one step late)

    for (int t = 0; t < T_; ++t) {
        // ---- deferred reduce+atomic for step t-1 (runs in this step's ph1 window) ----
        if (t) {
            float ps = psum_d;
            ps += __shfl_xor(ps, 16);
            ps += __shfl_xor(ps, 32);
            if (lane < 16)
                atomicAdd(&out[(size_t)(b * T_ + (t - 1)) * H_ + wv * 16 + lane], ps * (1.0f / 64.0f));
        }

        // ---- prefetch step t+1 inputs (never drained at BAR; consumed next iter) ----
        const int tn = (t + 1 < T_) ? t + 1 : t;
        const float* epn = ep0 + (size_t)tn * (B_ * K_ * H_);
        float enext[4];
        #pragma unroll
        for (int r = 0; r < 4; ++r) enext[r] = epn[r * H_];
        const float xw0n = bf2f(xwp[tn * U_]), xw1n = bf2f(xwp[tn * U_ + 16]);
        const float tsn = ts_lds[tn];

        // ---- ph1: GEMM1 particle part; acc init = xw (x-part + bias, precomputed) ----
        f32x4 acc0 = {xw0c, xw0c, xw0c, xw0c};
        f32x4 acc1 = {xw1c, xw1c, xw1c, xw1c};
        #pragma unroll
        for (int kt = 0; kt < 4; ++kt) {
            const short8 ap = *(const short8*)((const char*)p_bf + swzbyte_p(ln15, kt * 32 + l4 * 8));
            acc0 = MFMA16(ap, B1p[kt][0], acc0);
            acc1 = MFMA16(ap, B1p[kt][1], acc1);
        }
        #pragma unroll
        for (int r = 0; r < 4; ++r) {                 // C: row=(l>>4)*4+r, col=l&15
            const int row = l4 * 4 + r;
            const unsigned int q0 = f2bf(1.7159f * fast_tanh(0.666f * acc0[r]));
            const unsigned int q1 = f2bf(1.7159f * fast_tanh(0.666f * acc1[r]));
            // packed b32 write: cols (wv*32+ln15, wv*32+16+ln15) -> pos (2*ln15, 2*ln15+1)
            *(unsigned int*)((char*)bbk_bf + swzbyte_b(row, wv * 32 + 2 * ln15)) = q0 | (q1 << 16);
        }
        BAR();   // bbk visible

        // ---- ph2: GEMM2 (4 heads, own 16 h-cols) + in-register combine ----
        f32x4 a_f1 = zero4, a_f2 = zero4, a_ta = zero4, a_tb = zero4;
        #pragma unroll
        for (int kt = 0; kt < 8; ++kt) {
            const short8 a = *(const short8*)((const char*)bbk_bf + swzbyte_b(ln15, kt * 32 + l4 * 8));
            a_f1 = MFMA16(a, B2[0][kt], a_f1);
            a_f2 = MFMA16(a, B2[1][kt], a_f2);
            a_ta = MFMA16(a, B2[2][kt], a_ta);
            a_tb = MFMA16(a, B2[3][kt], a_tb);
        }
        const float sq = sqrtf(tscur);
        float psum = 0.f;
        const bool last = (t == T_ - 1);
        #pragma unroll
        for (int r = 0; r < 4; ++r) {
            const int row = l4 * 4 + r;
            const float f1v = fast_tanh(a_f1[r] + bf1c);
            const float f2v = fast_tanh(a_f2[r] + bf2c);
            const float tiv = fast_sigmoid((a_ta[r] + btac) * tscur + (a_tb[r] + btbc));
            const float np  = f1v + tiv * (f2v - f1v) + nscc * sq * ecur[r];
            *(unsigned short*)((char*)p_bf + swzbyte_p(row, hc)) = f2bf(np);
            psum += np;
            if (last)
                out[OUT_OFF_P + (size_t)(b * K_ + k0 + row) * H_ + hc] = np;
        }
        psum_d = psum;   // reduced after BAR (next iteration / tail)

        #pragma unroll
        for (int r = 0; r < 4; ++r) ecur[r] = enext[r];
        xw0c = xw0n; xw1c = xw1n;
        tscur = tsn;
        BAR();   // p writes visible for next step's ph1
    }

    // tail: reduce for t = T-1
    {
        float ps = psum_d;
        ps += __shfl_xor(ps, 16);
        ps += __shfl_xor(ps, 32);
        if (lane < 16)
            atomicAdd(&out[(size_t)(b * T_ + (T_ - 1)) * H_ + wv * 16 + lane], ps * (1.0f / 64.0f));
    }
}

extern "C" void kernel_launch(void* const* d_in, const int* in_sizes, int n_in,
                              void* d_out, int out_size, void* d_ws, size_t ws_size,
                              hipStream_t stream) {
    const float* x    = (const float*)d_in[0];
    const float* tsp  = (const float*)d_in[1];
    const float* eps  = (const float*)d_in[2];
    const float* Wb   = (const float*)d_in[3];
    const float* bb   = (const float*)d_in[4];
    const float* Wf1  = (const float*)d_in[5];
    const float* bf1  = (const float*)d_in[6];
    const float* Wf2  = (const float*)d_in[7];
    const float* bf2  = (const float*)d_in[8];
    const float* Wta  = (const float*)d_in[9];
    const float* bta  = (const float*)d_in[10];
    const float* Wtb  = (const float*)d_in[11];
    const float* btb  = (const float*)d_in[12];
    const float* nsc  = (const float*)d_in[13];
    float* out = (float*)d_out;
    unsigned short* xw = (unsigned short*)d_ws;   // B*T*U bf16 = 2MB scratch

    // outputs region is accumulated with atomics -> zero every launch
    (void)hipMemsetAsync(d_out, 0, (size_t)OUT_OFF_P * sizeof(float), stream);
    xw_kernel<<<dim3(256), dim3(256), 0, stream>>>(x, Wb, bb, xw);
    pf_kernel<<<dim3(64), dim3(NTHR), 0, stream>>>(
        xw, tsp, eps, Wb, Wf1, bf1, Wf2, bf2, Wta, bta, Wtb, btb, nsc, out);
}

// Round 16
// 493.776 us; speedup vs baseline: 1.5583x; 1.1189x over previous
//
#include <hip/hip_runtime.h>
#include <math.h>

typedef __attribute__((ext_vector_type(8))) short short8;
typedef __attribute__((ext_vector_type(4))) float f32x4;

#define B_ 16
#define T_ 256
#define I_ 64
#define H_ 128
#define K_ 64
#define U_ 256
#define KC 16
#define NTHR 512

#define OUT_OFF_P (B_*T_*H_)              /* 524288 */
#define OUT_OFF_LW (OUT_OFF_P + B_*K_*H_) /* 655360 */

__device__ __forceinline__ unsigned short f2bf(float x) {
    unsigned int u = __float_as_uint(x);
    u += 0x7fffu + ((u >> 16) & 1u);   // RNE for finite inputs
    return (unsigned short)(u >> 16);
}
__device__ __forceinline__ float bf2f(unsigned short u) {
    return __uint_as_float(((unsigned int)u) << 16);
}
__device__ __forceinline__ float fast_tanh(float x) {
    float e = __expf(2.0f * x);
    return 1.0f - 2.0f * __builtin_amdgcn_rcpf(e + 1.0f);
}
__device__ __forceinline__ float fast_sigmoid(float x) {
    return __builtin_amdgcn_rcpf(1.0f + __expf(-x));
}
// XOR-swizzle (R3/R6-proven): breaks row-stride bank collisions on ds_read_b128
__device__ __forceinline__ unsigned int swzbyte_p(unsigned int row, unsigned int col) { // [16][128] bf16
    return (row * 256u + col * 2u) ^ ((row & 7u) << 4);
}
__device__ __forceinline__ unsigned int swzbyte_b(unsigned int row, unsigned int pos) { // [16][256] bf16 (pos space)
    return (row * 512u + pos * 2u) ^ ((row & 7u) << 4);
}

// raw barrier: LDS-visibility only; vmem (eps/xw prefetch, atomics) stays in flight.
// trailing empty asm = compile-time fence so post-barrier LDS reads can't hoist.
#define BAR() do { asm volatile("s_waitcnt lgkmcnt(0)" ::: "memory"); \
                   __builtin_amdgcn_s_barrier(); \
                   asm volatile("" ::: "memory"); } while (0)

#define MFMA16(a, bfrag, c) __builtin_amdgcn_mfma_f32_16x16x32_bf16((a), (bfrag), (c), 0, 0, 0)

// ---------------- kernel 1: xw[b,t,u] = x[b,t,:] @ Wb[0:64,:] + bb  (bf16) ----------------
__global__ __launch_bounds__(256) void xw_kernel(
    const float* __restrict__ x, const float* __restrict__ Wb,
    const float* __restrict__ bb, unsigned short* __restrict__ xw)
{
    const int tid  = threadIdx.x;
    const int lane = tid & 63;
    const int wv   = tid >> 6;       // 0..3, owns cols [wv*64, +64)
    const int ln15 = lane & 15;
    const int l4   = lane >> 4;
    const int bid  = blockIdx.x;     // 256 blocks = b(16) x ttile(16)
    const int b    = bid >> 4;
    const int t0   = (bid & 15) * 16;

    short8 Bx[2][4];
    float bbc[4];
    #pragma unroll
    for (int kt = 0; kt < 2; ++kt) {
        #pragma unroll
        for (int ct = 0; ct < 4; ++ct) {
            short8 f;
            const int col = wv * 64 + ct * 16 + ln15;
            #pragma unroll
            for (int j = 0; j < 8; ++j)
                f[j] = (short)f2bf(Wb[(kt * 32 + l4 * 8 + j) * U_ + col]);
            Bx[kt][ct] = f;
        }
    }
    #pragma unroll
    for (int ct = 0; ct < 4; ++ct) bbc[ct] = bb[wv * 64 + ct * 16 + ln15];

    short8 ax[2];
    #pragma unroll
    for (int kt = 0; kt < 2; ++kt) {
        const float* xp = &x[(size_t)(b * T_ + t0 + ln15) * I_ + kt * 32 + l4 * 8];
        short8 f;
        #pragma unroll
        for (int j = 0; j < 8; ++j) f[j] = (short)f2bf(xp[j]);
        ax[kt] = f;
    }
    const f32x4 z4 = {0.f, 0.f, 0.f, 0.f};
    f32x4 acc[4] = {z4, z4, z4, z4};
    #pragma unroll
    for (int kt = 0; kt < 2; ++kt) {
        #pragma unroll
        for (int ct = 0; ct < 4; ++ct) acc[ct] = MFMA16(ax[kt], Bx[kt][ct], acc[ct]);
    }
    #pragma unroll
    for (int ct = 0; ct < 4; ++ct) {
        #pragma unroll
        for (int r = 0; r < 4; ++r) {
            const int trow = t0 + l4 * 4 + r;
            xw[(size_t)(b * T_ + trow) * U_ + wv * 64 + ct * 16 + ln15] = f2bf(acc[ct][r] + bbc[ct]);
        }
    }
}

// ---------------- kernel 2: the recurrence (R6: 2-barrier, in-tail reduce, scattered b16 writes) ----------------
__global__ __launch_bounds__(NTHR, 2) void pf_kernel(
    const unsigned short* __restrict__ xw, const float* __restrict__ tspan,
    const float* __restrict__ eps, const float* __restrict__ Wb,
    const float* __restrict__ Wf1, const float* __restrict__ bf1,
    const float* __restrict__ Wf2, const float* __restrict__ bf2,
    const float* __restrict__ Wta, const float* __restrict__ bta,
    const float* __restrict__ Wtb, const float* __restrict__ btb,
    const float* __restrict__ nscale, float* __restrict__ out)
{
    const int tid  = threadIdx.x;
    const int lane = tid & 63;
    const int wv   = tid >> 6;        // wave 0..7
    const int ln15 = lane & 15;
    const int l4   = lane >> 4;
    const int bid  = blockIdx.x;      // 0..63
    const int b    = bid >> 2;
    const int k0   = (bid & 3) * KC;

    __shared__ unsigned short p_bf[KC * H_];     // particles bf16, swizzled (4KB)
    __shared__ unsigned short bbk_bf[KC * U_];   // backbone acts bf16, swizzled + col-pair-permuted (8KB)
    __shared__ float ts_lds[T_];                 // (1KB)

    for (int i = tid; i < KC * H_; i += NTHR) p_bf[i] = 0;
    for (int i = tid; i < T_; i += NTHR) ts_lds[i] = tspan[b * T_ + i];

    // ---- GEMM1 particle-part weights (Wb rows 64..191), wave owns bbk cols [wv*32,+32) ----
    short8 B1p[4][2];
    #pragma unroll
    for (int kt = 0; kt < 4; ++kt) {
        #pragma unroll
        for (int ct = 0; ct < 2; ++ct) {
            short8 f;
            const int col = wv * 32 + ct * 16 + ln15;
            #pragma unroll
            for (int j = 0; j < 8; ++j)
                f[j] = (short)f2bf(Wb[(I_ + kt * 32 + l4 * 8 + j) * U_ + col]);
            B1p[kt][ct] = f;
        }
    }
    // ---- GEMM2 weights: wave owns h cols [wv*16,+16) for ALL 4 heads ----
    // bbk LDS is column-PERMUTED within each 32-block: col c -> pos 2*(c&15)+(c>>4),
    // so B-fragment element j (pos = l4*8+j) maps to k = kt*32 + (pos>>1) + ((pos&1)<<4).
    const float* Whp[4] = {Wf1, Wf2, Wta, Wtb};
    const int hc = wv * 16 + ln15;
    short8 B2[4][8];
    #pragma unroll
    for (int hd = 0; hd < 4; ++hd) {
        #pragma unroll
        for (int kt = 0; kt < 8; ++kt) {
            short8 f;
            #pragma unroll
            for (int j = 0; j < 8; ++j) {
                const int pos = l4 * 8 + j;
                const int kg  = kt * 32 + (pos >> 1) + ((pos & 1) << 4);
                f[j] = (short)f2bf(Whp[hd][kg * H_ + hc]);
            }
            B2[hd][kt] = f;
        }
    }
    const float bf1c = bf1[hc], bf2c = bf2[hc];
    const float btac = bta[hc], btbc = btb[hc];
    const float nscc = nscale[hc];

    if ((bid & 3) == 0 && tid < K_)
        out[OUT_OFF_LW + b * K_ + tid] = -4.1588830833596715f; // -log(64)

    __syncthreads();   // full drain once after prologue

    // per-step scalar operands, prefetched one step ahead into registers
    const float* ep0 = eps + ((size_t)(b * K_ + k0 + l4 * 4)) * H_ + hc;        // + t*B*K*H
    const unsigned short* xwp = xw + (size_t)b * T_ * U_ + wv * 32 + ln15;      // + t*U  (+16 for ct=1)
    float ecur[4];
    #pragma unroll
    for (int r = 0; r < 4; ++r) ecur[r] = ep0[r * H_];
    float xw0c = bf2f(xwp[0]), xw1c = bf2f(xwp[16]);
    float tscur = ts_lds[0];

    const f32x4 zero4 = {0.f, 0.f, 0.f, 0.f};

    for (int t = 0; t < T_; ++t) {
        // ---- prefetch step t+1 inputs (never drained at BAR; consumed next iter) ----
        const int tn = (t + 1 < T_) ? t + 1 : t;
        const float* epn = ep0 + (size_t)tn * (B_ * K_ * H_);
        float enext[4];
        #pragma unroll
        for (int r = 0; r < 4; ++r) enext[r] = epn[r * H_];
        const float xw0n = bf2f(xwp[tn * U_]), xw1n = bf2f(xwp[tn * U_ + 16]);
        const float tsn = ts_lds[tn];

        // ---- ph1: GEMM1 particle part; acc init = xw (x-part + bias, precomputed) ----
        f32x4 acc0 = {xw0c, xw0c, xw0c, xw0c};
        f32x4 acc1 = {xw1c, xw1c, xw1c, xw1c};
        #pragma unroll
        for (int kt = 0; kt < 4; ++kt) {
            const short8 ap = *(const short8*)((const char*)p_bf + swzbyte_p(ln15, kt * 32 + l4 * 8));
            acc0 = MFMA16(ap, B1p[kt][0], acc0);
            acc1 = MFMA16(ap, B1p[kt][1], acc1);
        }
        #pragma unroll
        for (int r = 0; r < 4; ++r) {                 // C: row=(l>>4)*4+r, col=l&15
            const int row = l4 * 4 + r;
            const unsigned int q0 = f2bf(1.7159f * fast_tanh(0.666f * acc0[r]));
            const unsigned int q1 = f2bf(1.7159f * fast_tanh(0.666f * acc1[r]));
            // packed write: cols (wv*32+ln15, wv*32+16+ln15) -> pos (2*ln15, 2*ln15+1)
            *(unsigned int*)((char*)bbk_bf + swzbyte_b(row, wv * 32 + 2 * ln15)) = q0 | (q1 << 16);
        }
        BAR();   // bbk visible

        // ---- ph2: GEMM2 (4 heads, own 16 h-cols) + in-register combine ----
        f32x4 a_f1 = zero4, a_f2 = zero4, a_ta = zero4, a_tb = zero4;
        #pragma unroll
        for (int kt = 0; kt < 8; ++kt) {
            const short8 a = *(const short8*)((const char*)bbk_bf + swzbyte_b(ln15, kt * 32 + l4 * 8));
            a_f1 = MFMA16(a, B2[0][kt], a_f1);
            a_f2 = MFMA16(a, B2[1][kt], a_f2);
            a_ta = MFMA16(a, B2[2][kt], a_ta);
            a_tb = MFMA16(a, B2[3][kt], a_tb);
        }
        const float sq = sqrtf(tscur);
        float psum = 0.f;
        const bool last = (t == T_ - 1);
        #pragma unroll
        for (int r = 0; r < 4; ++r) {
            const int row = l4 * 4 + r;
            const float f1v = fast_tanh(a_f1[r] + bf1c);
            const float f2v = fast_tanh(a_f2[r] + bf2c);
            const float tiv = fast_sigmoid((a_ta[r] + btac) * tscur + (a_tb[r] + btbc));
            const float np  = f1v + tiv * (f2v - f1v) + nscc * sq * ecur[r];
            *(unsigned short*)((char*)p_bf + swzbyte_p(row, hc)) = f2bf(np);
            psum += np;
            if (last)
                out[OUT_OFF_P + (size_t)(b * K_ + k0 + row) * H_ + hc] = np;
        }
        // block partial mean (16 rows): sum over l4 groups, 1 atomic per 16 lanes
        psum += __shfl_xor(psum, 16);
        psum += __shfl_xor(psum, 32);
        if (lane < 16)
            atomicAdd(&out[(size_t)(b * T_ + t) * H_ + wv * 16 + lane], psum * (1.0f / 64.0f));

        #pragma unroll
        for (int r = 0; r < 4; ++r) ecur[r] = enext[r];
        xw0c = xw0n; xw1c = xw1n;
        tscur = tsn;
        BAR();   // p writes visible for next step's ph1
    }
}

extern "C" void kernel_launch(void* const* d_in, const int* in_sizes, int n_in,
                              void* d_out, int out_size, void* d_ws, size_t ws_size,
                              hipStream_t stream) {
    const float* x    = (const float*)d_in[0];
    const float* tsp  = (const float*)d_in[1];
    const float* eps  = (const float*)d_in[2];
    const float* Wb   = (const float*)d_in[3];
    const float* bb   = (const float*)d_in[4];
    const float* Wf1  = (const float*)d_in[5];
    const float* bf1  = (const float*)d_in[6];
    const float* Wf2  = (const float*)d_in[7];
    const float* bf2  = (const float*)d_in[8];
    const float* Wta  = (const float*)d_in[9];
    const float* bta  = (const float*)d_in[10];
    const float* Wtb  = (const float*)d_in[11];
    const float* btb  = (const float*)d_in[12];
    const float* nsc  = (const float*)d_in[13];
    float* out = (float*)d_out;
    unsigned short* xw = (unsigned short*)d_ws;   // B*T*U bf16 = 2MB scratch

    // outputs region is accumulated with atomics -> zero every launch
    (void)hipMemsetAsync(d_out, 0, (size_t)OUT_OFF_P * sizeof(float), stream);
    xw_kernel<<<dim3(256), dim3(256), 0, stream>>>(x, Wb, bb, xw);
    pf_kernel<<<dim3(64), dim3(NTHR), 0, stream>>>(
        xw, tsp, eps, Wb, Wf1, bf1, Wf2, bf2, Wta, bta, Wtb, btb, nsc, out);
}